// Round 2
// baseline (191.905 us; speedup 1.0000x reference)
//
#include <hip/hip_runtime.h>

typedef __attribute__((ext_vector_type(8))) short short8;
typedef __attribute__((ext_vector_type(4))) float floatx4;

// Quantize one float to the PACT integer (q - zp) and return its exact bf16 bits.
// |q - zp| <= 256 -> integer is exact in bf16, so plain truncation of the fp32
// bits is exact (low 16 bits are already zero).
__device__ __forceinline__ unsigned short quant_bf16(float x, float cvn, float cv,
                                                     float scale, float zp) {
    float xc = fminf(fmaxf(x, cvn), cv);
    float q  = rintf(xc * scale + zp);   // RNE, matches jnp.round
    float v  = q - zp;                   // integer in [-256, 256]
    return (unsigned short)(__float_as_uint(v) >> 16);
}

// m1: [32][1024][128] fp32 -> qA same layout, bf16 integer values.
__global__ __launch_bounds__(256) void quant_m1_kernel(
        const float* __restrict__ x, unsigned short* __restrict__ q,
        const float* __restrict__ cvp, const float* __restrict__ cvnp, int n4) {
    int i = blockIdx.x * 256 + threadIdx.x;
    if (i >= n4) return;
    float cv = cvp[0], cvn = cvnp[0];
    float scale = 255.0f / (cv - cvn);
    float zp = rintf(-cvn * scale);
    floatx4 v = ((const floatx4*)x)[i];
    ushort4 o;
    o.x = quant_bf16(v[0], cvn, cv, scale, zp);
    o.y = quant_bf16(v[1], cvn, cv, scale, zp);
    o.z = quant_bf16(v[2], cvn, cv, scale, zp);
    o.w = quant_bf16(v[3], cvn, cv, scale, zp);
    ((ushort4*)q)[i] = o;
}

// m2: [32][128 d][1024 s] fp32 -> qBt: [32][1024 s][128 d] bf16 integer values.
// v2: 64-wide s-tiles (512 blocks), in-register 4x4 transpose, vectorized LDS
// (ds_write_b64 in, ds_read_b128 out), 16B coalesced stores.
__global__ __launch_bounds__(256) void quant_m2t_kernel(
        const float* __restrict__ x, unsigned short* __restrict__ qt,
        const float* __restrict__ cvp, const float* __restrict__ cvnp) {
    __shared__ unsigned short ldsT[64][136];  // [s][d]; stride 272B keeps rows 16B-aligned
    int batch = blockIdx.y;
    int s0 = blockIdx.x * 64;
    const float* xb = x + (size_t)batch * (128 * 1024);
    unsigned short* qb = qt + (size_t)batch * (1024 * 128);
    float cv = cvp[0], cvn = cvnp[0];
    float scale = 255.0f / (cv - cvn);
    float zp = rintf(-cvn * scale);
    int t = threadIdx.x;
#pragma unroll
    for (int r = 0; r < 2; ++r) {
        int u = t + 256 * r;      // 512 units of 4d x 4s
        int su = u & 15;          // s-chunk (lanes consecutive in s -> coalesced)
        int du = u >> 4;          // d-chunk 0..31
        floatx4 v[4];
#pragma unroll
        for (int i = 0; i < 4; ++i)
            v[i] = *(const floatx4*)(xb + (size_t)(du * 4 + i) * 1024 + s0 + su * 4);
#pragma unroll
        for (int j = 0; j < 4; ++j) {
            ushort4 w;
            w.x = quant_bf16(v[0][j], cvn, cv, scale, zp);
            w.y = quant_bf16(v[1][j], cvn, cv, scale, zp);
            w.z = quant_bf16(v[2][j], cvn, cv, scale, zp);
            w.w = quant_bf16(v[3][j], cvn, cv, scale, zp);
            *(ushort4*)&ldsT[su * 4 + j][du * 4] = w;  // 8B LDS write
        }
    }
    __syncthreads();
#pragma unroll
    for (int r = 0; r < 4; ++r) {
        int c = t + 256 * r;      // 1024 chunks of 16B
        int sl = c >> 4, k8 = c & 15;
        *(short8*)(qb + (size_t)(s0 + sl) * 128 + k8 * 8) =
            *(const short8*)&ldsT[sl][k8 * 8];         // b128 read, coalesced store
    }
}

// Batched GEMM: C[b][s][t] = (sum_d qa[s][d]*qbt[t][d]) * inv_scale.
// 128x128 tile/block, 4 waves (2x2), 4x4 MFMA 16x16x32 tiles/wave, K=128 fully
// unrolled, fragments direct from global (both operands k-contiguous, 16B loads).
// v2: no min-wave launch bound (avoid VGPR cap -> scratch spills of the frag
// working set); mfma(b,a,.) computes C^T in fragment space, which lands each
// lane's 4 acc regs on 4 consecutive C columns -> single dwordx4 store per tile.
__global__ __launch_bounds__(256) void qbmm_kernel(
        const unsigned short* __restrict__ qA, const unsigned short* __restrict__ qBt,
        float* __restrict__ C,
        const float* __restrict__ cv1p, const float* __restrict__ cvn1p,
        const float* __restrict__ cv2p, const float* __restrict__ cvn2p) {
    int batch = blockIdx.z;
    const unsigned short* A  = qA  + (size_t)batch * (1024 * 128);
    const unsigned short* Bt = qBt + (size_t)batch * (1024 * 128);
    float* Cb = C + (size_t)batch * (1024 * 1024);
    int m0 = blockIdx.y * 128, n0 = blockIdx.x * 128;
    int tid = threadIdx.x;
    int lane = tid & 63, w = tid >> 6;
    int wr = w >> 1, wc = w & 1;
    int row16 = lane & 15, quad = lane >> 4;
    int wm = m0 + wr * 64, wn = n0 + wc * 64;

    floatx4 acc[4][4] = {};

    const short8* Ap[4];
    const short8* Bp[4];
#pragma unroll
    for (int i = 0; i < 4; ++i) {
        // A fragment: A[m = wm+i*16+row16][k = quad*8 + j], j contiguous
        Ap[i] = (const short8*)(A  + (size_t)(wm + i * 16 + row16) * 128 + quad * 8);
        // B fragment (from transposed qBt): B[k][n=wn+i*16+row16] = qBt[n][k]
        Bp[i] = (const short8*)(Bt + (size_t)(wn + i * 16 + row16) * 128 + quad * 8);
    }

#pragma unroll
    for (int kk = 0; kk < 4; ++kk) {          // k-step of 32
        short8 a[4], b[4];
#pragma unroll
        for (int i = 0; i < 4; ++i) { a[i] = Ap[i][kk * 4]; b[i] = Bp[i][kk * 4]; }
#pragma unroll
        for (int mi = 0; mi < 4; ++mi)
#pragma unroll
            for (int ni = 0; ni < 4; ++ni)
                // D = (B^T)(A^T) = C^T tile: lane reg r = C[s=mi*16+row16][t=ni*16+quad*4+r]
                acc[mi][ni] = __builtin_amdgcn_mfma_f32_16x16x32_bf16(
                    b[ni], a[mi], acc[mi][ni], 0, 0, 0);
    }

    // inv = 1/(scale1*scale2) = (cv1-cvn1)*(cv2-cvn2)/255^2
    float inv = (cv1p[0] - cvn1p[0]) * (cv2p[0] - cvn2p[0]) * (1.0f / 65025.0f);

#pragma unroll
    for (int mi = 0; mi < 4; ++mi) {
        int s = wm + mi * 16 + row16;
        float* crow = Cb + (size_t)s * 1024;
#pragma unroll
        for (int ni = 0; ni < 4; ++ni) {
            floatx4 o = acc[mi][ni] * inv;
            *(floatx4*)(crow + wn + ni * 16 + quad * 4) = o;   // 16B store
        }
    }
}

extern "C" void kernel_launch(void* const* d_in, const int* in_sizes, int n_in,
                              void* d_out, int out_size, void* d_ws, size_t ws_size,
                              hipStream_t stream) {
    const float* m1   = (const float*)d_in[0];
    const float* m2   = (const float*)d_in[1];
    const float* cv1  = (const float*)d_in[2];
    const float* cvn1 = (const float*)d_in[3];
    const float* cv2  = (const float*)d_in[4];
    const float* cvn2 = (const float*)d_in[5];
    float* out = (float*)d_out;

    unsigned short* qA  = (unsigned short*)d_ws;   // 4.19M bf16 = 8.39 MB
    unsigned short* qBt = qA + 4194304;            // 8.39 MB, transposed m2

    // m1: 4194304 floats -> 1048576 float4s
    quant_m1_kernel<<<4096, 256, 0, stream>>>(m1, qA, cv1, cvn1, 1048576);
    // m2: 32 batches x (16 column-tiles of 64)
    quant_m2t_kernel<<<dim3(16, 32), 256, 0, stream>>>(m2, qBt, cv2, cvn2);
    // GEMM: 8x8 tiles x 32 batches
    qbmm_kernel<<<dim3(8, 8, 32), 256, 0, stream>>>(qA, qBt, out,
                                                    cv1, cvn1, cv2, cvn2);
}